// Round 8
// baseline (300.056 us; speedup 1.0000x reference)
//
#include <hip/hip_runtime.h>
#include <math.h>

#define NR 4096
#define HD 512
#define NJR 32
#define NBLK 512
#define INV_T 10.0f

typedef __attribute__((ext_vector_type(8))) short bf16x8;
typedef __attribute__((ext_vector_type(4))) short short4v;
typedef __attribute__((ext_vector_type(4))) float f32x4;

typedef const unsigned int __attribute__((address_space(1)))* gas_t;
typedef unsigned int __attribute__((address_space(3)))* las_t;

__device__ __forceinline__ unsigned short f2bf(float f) {
  union { float f; unsigned u; } v; v.f = f;
  unsigned r = v.u + 0x7fff + ((v.u >> 16) & 1);
  return (unsigned short)(r >> 16);
}
__device__ __forceinline__ float bf2f(unsigned short b) {
  union { unsigned u; float f; } v; v.u = ((unsigned)b) << 16;
  return v.f;
}

// ======== fragment-major layout ========
// matrix [M][K]: fragment (rf=r>>4, ks=c>>5) = 1024B slot at (rf*(K>>5)+ks)*1024.
// lane l holds bf16x8 at lane*16: row = rf*16+(l&15), cols ks*32+(l>>4)*4+{0..3,16..19}.

// ---------------------------------------------------------------- grid barrier
__device__ __forceinline__ void gridbar(unsigned* cnt, unsigned target) {
  __syncthreads();                       // drains each wave's stores (vmcnt0 at barrier)
  if (threadIdx.x == 0) {
    __threadfence();                     // release: writeback local XCD L2
    __hip_atomic_fetch_add(cnt, 1u, __ATOMIC_RELAXED, __HIP_MEMORY_SCOPE_AGENT);
    while (__hip_atomic_load(cnt, __ATOMIC_RELAXED, __HIP_MEMORY_SCOPE_AGENT) < target)
      __builtin_amdgcn_s_sleep(8);
    __threadfence();                     // acquire: invalidate local L1/L2
  }
  __syncthreads();
}

// ---------------------------------------------------------------- P0: prep unit
__device__ __forceinline__ void prep_unit(int b, int tid,
    const float* s, const float* sp, const float* a1h,
    unsigned short* Sb, unsigned short* SPb, int* aidx,
    const float* pW0, unsigned short* pW0t, const float* pW1, unsigned short* pW1t,
    const float* pW2, unsigned short* pW2t, const float* gW0, unsigned short* gW0t,
    const float* gW1, unsigned short* gW1t, const float* gW2, unsigned short* gW2t,
    float* out) {
  if (b < 16) {
    int r = b * 256 + tid;
    int a = 0;
#pragma unroll
    for (int j = 0; j < 4; ++j) if (a1h[(size_t)r * 4 + j] > 0.5f) a = j;
    aidx[r] = a;
    if (b == 0 && tid == 0) out[0] = 0.f;
    return;
  }
  const int idx8 = tid & 127;
  const int h = idx8 & 1, p = idx8 >> 1, hi = p >> 4, l15 = p & 15;
  if (b < 2064) {
    const float* src = (b < 1040) ? s : sp;
    unsigned short* dst = (b < 1040) ? Sb : SPb;
    int lb = (b < 1040) ? b - 16 : b - 1040;
    int s0 = lb * 2 + (tid >> 7);
    int rf = s0 >> 3, ks = s0 & 7;
    int row = rf * 16 + l15, c0 = ks * 32 + hi * 4 + h * 16;
    float4 v = *(const float4*)&src[(size_t)row * 256 + c0];
    short4v o = { (short)f2bf(v.x), (short)f2bf(v.y), (short)f2bf(v.z), (short)f2bf(v.w) };
    *(short4v*)((char*)dst + (size_t)s0 * 1024 + idx8 * 8) = o;
    return;
  }
  int local = b - 2064;
  const float* W; unsigned short* Wt; int N, ksh;
  if (local < 128)      { W = pW0; Wt = pW0t; N = 512; ksh = 3; }
  else if (local < 384) { W = pW1; Wt = pW1t; N = 512; ksh = 4; local -= 128; }
  else if (local < 448) { W = pW2; Wt = pW2t; N = 128; ksh = 4; local -= 384; }
  else if (local < 576) { W = gW0; Wt = gW0t; N = 512; ksh = 3; local -= 448; }
  else if (local < 832) { W = gW1; Wt = gW1t; N = 512; ksh = 4; local -= 576; }
  else                  { W = gW2; Wt = gW2t; N = 128; ksh = 4; local -= 832; }
  int s0 = local * 2 + (tid >> 7);
  int rf = s0 >> ksh, ks = s0 & ((1 << ksh) - 1);
  int n = rf * 16 + l15, k0 = ks * 32 + hi * 4 + h * 16;
  short4v o = { (short)f2bf(W[(size_t)(k0 + 0) * N + n]),
                (short)f2bf(W[(size_t)(k0 + 1) * N + n]),
                (short)f2bf(W[(size_t)(k0 + 2) * N + n]),
                (short)f2bf(W[(size_t)(k0 + 3) * N + n]) };
  *(short4v*)((char*)Wt + (size_t)s0 * 1024 + idx8 * 8) = o;
}

// ---------------------------------------------------------------- GEMM phase (2-deep gload_lds pipeline)
template <int BM, int K, bool RELU, bool GB, bool SQ>
__device__ __forceinline__ void gemm_phase(
    int bx, int by, bool gb1, char* lds,
    const char* Ab, const char* Wb, const float* bias, char* Cb,
    float* sqp2, int N, const int* aidx, const float* gW0f, int tid) {
  constexpr int KS = K >> 5;
  constexpr int NSTEP = K >> 6;
  constexpr int ABYTES = BM * 128;
  constexpr int BBYTES = 8192;
  constexpr int NA = BM >> 5;
  constexpr int WM_FR = BM >> 5;
  constexpr int V = NA + 2;
  char* AsB = lds;
  char* BsB = lds + 2 * ABYTES;
  const int lane = tid & 63, w = tid >> 6;
  const int wm = w >> 1, wn = w & 1;
  const int bm = bx * BM, bn = by * 64;
  const int lane16 = lane * 16;

  auto stage = [&](int buf, int st) {
#pragma unroll
    for (int u = 0; u < NA; ++u) {
      const int sl = w * NA + u;
      const char* src = Ab + ((size_t)((bm >> 4) + (sl >> 1)) * KS + st * 2 + (sl & 1)) * 1024 + lane16;
      __builtin_amdgcn_global_load_lds((gas_t)src, (las_t)(AsB + buf * ABYTES + sl * 1024), 16, 0, 0);
    }
#pragma unroll
    for (int u = 0; u < 2; ++u) {
      const int sl = w * 2 + u;
      const char* src = Wb + ((size_t)((bn >> 4) + (sl >> 1)) * KS + st * 2 + (sl & 1)) * 1024 + lane16;
      __builtin_amdgcn_global_load_lds((gas_t)src, (las_t)(BsB + buf * BBYTES + sl * 1024), 16, 0, 0);
    }
  };

  f32x4 acc[WM_FR][2] = {};
  stage(0, 0);
#pragma unroll
  for (int st = 0; st < NSTEP; ++st) {
    const int buf = st & 1;
    if (st + 1 < NSTEP) {
      stage(buf ^ 1, st + 1);
      if constexpr (V == 6) asm volatile("s_waitcnt vmcnt(6)" ::: "memory");
      else                  asm volatile("s_waitcnt vmcnt(4)" ::: "memory");
    } else {
      asm volatile("s_waitcnt vmcnt(0)" ::: "memory");
    }
    __builtin_amdgcn_s_barrier();
#pragma unroll
    for (int kss = 0; kss < 2; ++kss) {
      bf16x8 af[WM_FR], bfv[2];
#pragma unroll
      for (int i = 0; i < WM_FR; ++i)
        af[i] = *(const bf16x8*)(AsB + buf * ABYTES + ((wm * WM_FR + i) * 2 + kss) * 1024 + lane16);
#pragma unroll
      for (int j = 0; j < 2; ++j)
        bfv[j] = *(const bf16x8*)(BsB + buf * BBYTES + ((wn * 2 + j) * 2 + kss) * 1024 + lane16);
#pragma unroll
      for (int i = 0; i < WM_FR; ++i)
#pragma unroll
        for (int j = 0; j < 2; ++j)
          acc[i][j] = __builtin_amdgcn_mfma_f32_16x16x32_bf16(bfv[j], af[i], acc[i][j], 0, 0, 0);
    }
    __builtin_amdgcn_s_barrier();
  }

  const int l15 = lane & 15, hi = lane >> 4;
  const int NS = N >> 5;
  const int row0 = bm + wm * (BM / 2);
  const int col0 = bn + wn * 32;
  float sq[WM_FR];
  int ar[WM_FR];
#pragma unroll
  for (int i = 0; i < WM_FR; ++i) { sq[i] = 0.f; ar[i] = 0; }
  if (GB && gb1) {
#pragma unroll
    for (int i = 0; i < WM_FR; ++i) ar[i] = aidx[row0 + i * 16 + l15];
  }
  float4 bi0 = *(const float4*)&bias[col0 + hi * 4];
  float4 bi1 = *(const float4*)&bias[col0 + 16 + hi * 4];
#pragma unroll
  for (int i = 0; i < WM_FR; ++i) {
    const int rfC = (row0 >> 4) + i;
    float v[8] = { acc[i][0][0] + bi0.x, acc[i][0][1] + bi0.y,
                   acc[i][0][2] + bi0.z, acc[i][0][3] + bi0.w,
                   acc[i][1][0] + bi1.x, acc[i][1][1] + bi1.y,
                   acc[i][1][2] + bi1.z, acc[i][1][3] + bi1.w };
    if (GB && gb1) {
      float4 g0 = *(const float4*)&gW0f[(size_t)(256 + ar[i]) * N + col0 + hi * 4];
      float4 g1 = *(const float4*)&gW0f[(size_t)(256 + ar[i]) * N + col0 + 16 + hi * 4];
      v[0] += g0.x; v[1] += g0.y; v[2] += g0.z; v[3] += g0.w;
      v[4] += g1.x; v[5] += g1.y; v[6] += g1.z; v[7] += g1.w;
    }
    bf16x8 r;
#pragma unroll
    for (int t = 0; t < 8; ++t) {
      float vv = RELU ? fmaxf(v[t], 0.f) : v[t];
      unsigned short cv = f2bf(vv);
      r[t] = (short)cv;
      if (SQ) { float vb = bf2f(cv); sq[i] += vb * vb; }
    }
    *(bf16x8*)(Cb + (size_t)(rfC * NS + (col0 >> 5)) * 1024 + lane16) = r;
  }
  if (SQ && gb1) {
#pragma unroll
    for (int i = 0; i < WM_FR; ++i) {
      float t = sq[i];
      t += __shfl_xor(t, 16, 64);
      t += __shfl_xor(t, 32, 64);
      if (lane < 16) sqp2[(size_t)(col0 >> 5) * NR + row0 + i * 16 + lane] = t;
    }
  }
}

// ---------------------------------------------------------------- P4: logits (no LDS, swapped operands)
__device__ __forceinline__ void logits_phase(int bid, int tid,
    const unsigned short* Zb, const unsigned short* Zpb, const float* sqp2,
    float* wmm, float* wsum, float* wdiag) {
  const int lane = tid & 63, w = tid >> 6;
  const int l15 = lane & 15, hi = lane >> 4;
  const int x = bid & 31, jr0 = bid >> 5;
  const int row32 = x * 128 + w * 32;
  const int lane16 = lane * 16;
  const char* Zc = (const char*)Zb;
  const char* Pc = (const char*)Zpb;

  bf16x8 afr[2][4];
#pragma unroll
  for (int rf = 0; rf < 2; ++rf)
#pragma unroll
    for (int ks = 0; ks < 4; ++ks)
      afr[rf][ks] = *(const bf16x8*)(Zc + (size_t)(((row32 >> 4) + rf) * 4 + ks) * 1024 + lane16);

#pragma unroll
  for (int it = 0; it < 2; ++it) {
    const int jr = jr0 + it * 16;
    const int jbase = jr * 128;
    f32x4 acc[2][8] = {};
#pragma unroll
    for (int jf = 0; jf < 8; ++jf) {
      const size_t js = (size_t)((jbase >> 4) + jf) * 4;
#pragma unroll
      for (int ks = 0; ks < 4; ++ks) {
        bf16x8 bfv = *(const bf16x8*)(Pc + (js + ks) * 1024 + lane16);
        acc[0][jf] = __builtin_amdgcn_mfma_f32_16x16x32_bf16(bfv, afr[0][ks], acc[0][jf], 0, 0, 0);
        acc[1][jf] = __builtin_amdgcn_mfma_f32_16x16x32_bf16(bfv, afr[1][ks], acc[1][jf], 0, 0, 0);
      }
    }
#pragma unroll
    for (int rf = 0; rf < 2; ++rf) {
      const int grow = row32 + rf * 16 + l15;
      float mx = -INFINITY, dd = 0.f;
      bool hasd = false;
#pragma unroll
      for (int jf = 0; jf < 8; ++jf) {
        const int cb = jbase + jf * 16 + hi * 4;
        float4 q0 = *(const float4*)&sqp2[cb];
        float4 q1 = *(const float4*)&sqp2[NR + cb];
        float4 q2 = *(const float4*)&sqp2[2 * NR + cb];
        float4 q3 = *(const float4*)&sqp2[3 * NR + cb];
        float sp[4] = { q0.x + q1.x + q2.x + q3.x, q0.y + q1.y + q2.y + q3.y,
                        q0.z + q1.z + q2.z + q3.z, q0.w + q1.w + q2.w + q3.w };
#pragma unroll
        for (int e = 0; e < 4; ++e) {
          float lv = (2.f * acc[rf][jf][e] - sp[e]) * INV_T;
          acc[rf][jf][e] = lv;
          mx = fmaxf(mx, lv);
          if (cb + e == grow) { dd = lv; hasd = true; }
        }
      }
      mx = fmaxf(mx, __shfl_xor(mx, 16, 64));
      mx = fmaxf(mx, __shfl_xor(mx, 32, 64));
      float sum = 0.f;
#pragma unroll
      for (int jf = 0; jf < 8; ++jf)
#pragma unroll
        for (int e = 0; e < 4; ++e) sum += __expf(acc[rf][jf][e] - mx);
      sum += __shfl_xor(sum, 16, 64);
      sum += __shfl_xor(sum, 32, 64);
      if (hi == 0) {
        wmm[(size_t)jr * NR + grow] = mx;
        wsum[(size_t)jr * NR + grow] = sum;
      }
      if (hasd) wdiag[grow] = dd;
    }
  }
}

// ---------------------------------------------------------------- P5: finalize (8 rows/block)
__device__ __forceinline__ void finalize_phase(int bid, int tid, char* smem,
    const float* wmm, const float* wsum, const float* wdiag, float* out) {
  float* part = (float*)smem;
  const int rloc = tid >> 5, pp = tid & 31;
  const int r = bid * 8 + rloc;
  float mm = wmm[(size_t)pp * NR + r];
  float ss = wsum[(size_t)pp * NR + r];
#pragma unroll
  for (int off = 16; off >= 1; off >>= 1) {
    float mo = __shfl_xor(mm, off, 64);
    float so = __shfl_xor(ss, off, 64);
    float mn = fmaxf(mm, mo);
    ss = ss * __expf(mm - mn) + so * __expf(mo - mn);
    mm = mn;
  }
  if (pp == 0) part[rloc] = mm + logf(ss) - wdiag[r];
  __syncthreads();
  if (tid == 0) {
    float t = 0.f;
#pragma unroll
    for (int i = 0; i < 8; ++i) t += part[i];
    atomicAdd(out, t * (1.0f / (float)NR));
  }
}

// ---------------------------------------------------------------- megakernel
__global__ __launch_bounds__(256, 2) void nachum_mega(
    const float* s, const float* sp, const float* a1h,
    const float* pW0, const float* pb0, const float* pW1, const float* pb1,
    const float* pW2, const float* pb2,
    const float* gW0, const float* gb0, const float* gW1, const float* gb1,
    const float* gW2, const float* gb2,
    unsigned short* Sb, unsigned short* SPb,
    unsigned short* H1, unsigned short* H1g, unsigned short* H2, unsigned short* H2g,
    unsigned short* Zb, unsigned short* Zpb,
    unsigned short* pW0t, unsigned short* pW1t, unsigned short* pW2t,
    unsigned short* gW0t, unsigned short* gW1t, unsigned short* gW2t,
    float* sqp2, float* wmm, float* wsum, float* wdiag, int* aidx,
    unsigned* cnt, float* out) {
  __shared__ __align__(1024) char smem[49152];
  const int bid = blockIdx.x, tid = threadIdx.x;

  // P0: casts + weight transposes + out zero
  for (int u = bid; u < 2960; u += NBLK)
    prep_unit(u, tid, s, sp, a1h, Sb, SPb, aidx,
              pW0, pW0t, pW1, pW1t, pW2, pW2t, gW0, gW0t, gW1, gW1t, gW2, gW2t, out);
  gridbar(cnt, NBLK);

  // P1: layer 0 (K=256, N=512), virtual grid (32,8,2)
  {
    int x = bid & 31, y = (bid >> 5) & 7, z = bid >> 8;
    gemm_phase<128, 256, true, true, false>(
        x, y, z == 1, smem,
        (const char*)(z ? SPb : Sb), (const char*)(z ? gW0t : pW0t),
        z ? gb0 : pb0, (char*)(z ? H1g : H1),
        nullptr, 512, aidx, gW0, tid);
  }
  gridbar(cnt, 2 * NBLK);

  // P2: layer 1 (K=512, N=512)
  {
    int x = bid & 31, y = (bid >> 5) & 7, z = bid >> 8;
    gemm_phase<128, 512, true, false, false>(
        x, y, false, smem,
        (const char*)(z ? H1g : H1), (const char*)(z ? gW1t : pW1t),
        z ? gb1 : pb1, (char*)(z ? H2g : H2),
        nullptr, 512, nullptr, nullptr, tid);
  }
  gridbar(cnt, 3 * NBLK);

  // P3: layer 2 (K=512, N=128) + row-norm partials; 256 virtual blocks
  if (bid < 256) {
    int x = bid & 63, y = (bid >> 6) & 1, z = bid >> 7;
    gemm_phase<64, 512, false, false, true>(
        x, y, z == 1, smem,
        (const char*)(z ? H2g : H2), (const char*)(z ? gW2t : pW2t),
        z ? gb2 : pb2, (char*)(z ? Zpb : Zb),
        sqp2, 128, nullptr, nullptr, tid);
  }
  gridbar(cnt, 4 * NBLK);

  // P4: logits + per-(row, jr) softmax partials
  logits_phase(bid, tid, Zb, Zpb, sqp2, wmm, wsum, wdiag);
  gridbar(cnt, 5 * NBLK);

  // P5: combine partials, accumulate loss
  finalize_phase(bid, tid, smem, wmm, wsum, wdiag, out);
}

// ---------------------------------------------------------------- launch
extern "C" void kernel_launch(void* const* d_in, const int* in_sizes, int n_in,
                              void* d_out, int out_size, void* d_ws, size_t ws_size,
                              hipStream_t stream) {
  const float* s   = (const float*)d_in[0];
  const float* sp  = (const float*)d_in[1];
  const float* a1h = (const float*)d_in[2];
  const float* pW0 = (const float*)d_in[3];
  const float* pb0 = (const float*)d_in[4];
  const float* pW1 = (const float*)d_in[5];
  const float* pb1 = (const float*)d_in[6];
  const float* pW2 = (const float*)d_in[7];
  const float* pb2 = (const float*)d_in[8];
  const float* gW0 = (const float*)d_in[9];
  const float* gb0 = (const float*)d_in[10];
  const float* gW1 = (const float*)d_in[11];
  const float* gb1 = (const float*)d_in[12];
  const float* gW2 = (const float*)d_in[13];
  const float* gb2 = (const float*)d_in[14];

  char* p = (char*)d_ws;
  unsigned short* Sb   = (unsigned short*)p; p += (size_t)NR * 256 * 2;
  unsigned short* SPb  = (unsigned short*)p; p += (size_t)NR * 256 * 2;
  unsigned short* H1   = (unsigned short*)p; p += (size_t)2 * NR * HD * 2;
  unsigned short* H2   = (unsigned short*)p; p += (size_t)2 * NR * HD * 2;
  unsigned short* Zall = (unsigned short*)p; p += (size_t)2 * NR * 128 * 2;
  unsigned short* pW0t = (unsigned short*)p; p += (size_t)256 * 512 * 2;
  unsigned short* pW1t = (unsigned short*)p; p += (size_t)512 * 512 * 2;
  unsigned short* pW2t = (unsigned short*)p; p += (size_t)512 * 128 * 2;
  unsigned short* gW0t = (unsigned short*)p; p += (size_t)256 * 512 * 2;
  unsigned short* gW1t = (unsigned short*)p; p += (size_t)512 * 512 * 2;
  unsigned short* gW2t = (unsigned short*)p; p += (size_t)512 * 128 * 2;
  float* sqp2 = (float*)p; p += (size_t)4 * NR * 4;
  float* wmm  = (float*)p; p += (size_t)NJR * NR * 4;
  float* wsm  = (float*)p; p += (size_t)NJR * NR * 4;
  float* wdg  = (float*)p; p += (size_t)NR * 4;
  int*   aidx = (int*)p;  p += (size_t)NR * 4;
  unsigned* cnt = (unsigned*)p; p += 64;

  unsigned short* H1g = H1 + (size_t)NR * HD;
  unsigned short* H2g = H2 + (size_t)NR * HD;
  unsigned short* Zb  = Zall;
  unsigned short* Zpb = Zall + (size_t)NR * 128;

  hipMemsetAsync(cnt, 0, 64, stream);
  nachum_mega<<<NBLK, 256, 0, stream>>>(
      s, sp, a1h, pW0, pb0, pW1, pb1, pW2, pb2,
      gW0, gb0, gW1, gb1, gW2, gb2,
      Sb, SPb, H1, H1g, H2, H2g, Zb, Zpb,
      pW0t, pW1t, pW2t, gW0t, gW1t, gW2t,
      sqp2, wmm, wsm, wdg, aidx, cnt, (float*)d_out);
}

// Round 9
// 71.193 us; speedup vs baseline: 4.2147x; 4.2147x over previous
//
#include <hip/hip_runtime.h>
#include <math.h>

#define NR 4096
#define HD 512
#define NJR 32
#define INV_T 10.0f

typedef __attribute__((ext_vector_type(8))) short bf16x8;
typedef __attribute__((ext_vector_type(4))) short short4v;
typedef __attribute__((ext_vector_type(4))) float f32x4;

__device__ __forceinline__ unsigned short f2bf(float f) {
  union { float f; unsigned u; } v; v.f = f;
  unsigned r = v.u + 0x7fff + ((v.u >> 16) & 1);
  return (unsigned short)(r >> 16);
}
__device__ __forceinline__ float bf2f(unsigned short b) {
  union { unsigned u; float f; } v; v.u = ((unsigned)b) << 16;
  return v.f;
}

// ======== fragment-major layout ========
// matrix [M][K]: fragment (rf=r>>4, ks=c>>5) = 1024B slot at (rf*(K>>5)+ks)*1024.
// lane l holds bf16x8 at lane*16: row = rf*16+(l&15), cols ks*32+(l>>4)*4+{0..3,16..19}.

// ---------------------------------------------------------------- prep (R7 verbatim)
__global__ __launch_bounds__(256) void prep(
    const float* __restrict__ s, const float* __restrict__ sp,
    const float* __restrict__ a1h,
    unsigned short* __restrict__ Sb, unsigned short* __restrict__ SPb,
    int* __restrict__ aidx,
    const float* __restrict__ pW0, unsigned short* __restrict__ pW0t,
    const float* __restrict__ pW1, unsigned short* __restrict__ pW1t,
    const float* __restrict__ pW2, unsigned short* __restrict__ pW2t,
    const float* __restrict__ gW0, unsigned short* __restrict__ gW0t,
    const float* __restrict__ gW1, unsigned short* __restrict__ gW1t,
    const float* __restrict__ gW2, unsigned short* __restrict__ gW2t,
    float* __restrict__ out) {
  int b = blockIdx.x, tid = threadIdx.x;
  if (b < 16) {
    int r = b * 256 + tid;
    int a = 0;
#pragma unroll
    for (int j = 0; j < 4; ++j) if (a1h[(size_t)r * 4 + j] > 0.5f) a = j;
    aidx[r] = a;
    if (b == 0 && tid == 0) out[0] = 0.f;
    return;
  }
  const int idx8 = tid & 127;
  const int h = idx8 & 1, p = idx8 >> 1, hi = p >> 4, l15 = p & 15;
  if (b < 2064) {
    const float* src = (b < 1040) ? s : sp;
    unsigned short* dst = (b < 1040) ? Sb : SPb;
    int lb = (b < 1040) ? b - 16 : b - 1040;
    int s0 = lb * 2 + (tid >> 7);
    int rf = s0 >> 3, ks = s0 & 7;
    int row = rf * 16 + l15, c0 = ks * 32 + hi * 4 + h * 16;
    float4 v = *(const float4*)&src[(size_t)row * 256 + c0];
    short4v o = { (short)f2bf(v.x), (short)f2bf(v.y), (short)f2bf(v.z), (short)f2bf(v.w) };
    *(short4v*)((char*)dst + (size_t)s0 * 1024 + idx8 * 8) = o;
    return;
  }
  int local = b - 2064;
  const float* W; unsigned short* Wt; int N, ksh;
  if (local < 128)      { W = pW0; Wt = pW0t; N = 512; ksh = 3; }
  else if (local < 384) { W = pW1; Wt = pW1t; N = 512; ksh = 4; local -= 128; }
  else if (local < 448) { W = pW2; Wt = pW2t; N = 128; ksh = 4; local -= 384; }
  else if (local < 576) { W = gW0; Wt = gW0t; N = 512; ksh = 3; local -= 448; }
  else if (local < 832) { W = gW1; Wt = gW1t; N = 512; ksh = 4; local -= 576; }
  else                  { W = gW2; Wt = gW2t; N = 128; ksh = 4; local -= 832; }
  int s0 = local * 2 + (tid >> 7);
  int rf = s0 >> ksh, ks = s0 & ((1 << ksh) - 1);
  int n = rf * 16 + l15, k0 = ks * 32 + hi * 4 + h * 16;
  short4v o = { (short)f2bf(W[(size_t)(k0 + 0) * N + n]),
                (short)f2bf(W[(size_t)(k0 + 1) * N + n]),
                (short)f2bf(W[(size_t)(k0 + 2) * N + n]),
                (short)f2bf(W[(size_t)(k0 + 3) * N + n]) };
  *(short4v*)((char*)Wt + (size_t)s0 * 1024 + idx8 * 8) = o;
}

// ---------------------------------------------------------------- fused 3-layer MLP
// grid (NR/32, 2). Block: 32 rows x full width; H1/H2 tiles (32KB) in LDS.
// Each wave owns a column slice: L0/L1 -> 128 cols (8 frags), L2 -> 32 cols.
__global__ __launch_bounds__(256) void mlp_fused(
    const unsigned short* __restrict__ Sb, const unsigned short* __restrict__ SPb,
    const unsigned short* __restrict__ pW0t, const unsigned short* __restrict__ pW1t,
    const unsigned short* __restrict__ pW2t,
    const unsigned short* __restrict__ gW0t, const unsigned short* __restrict__ gW1t,
    const unsigned short* __restrict__ gW2t,
    const float* __restrict__ pb0, const float* __restrict__ pb1,
    const float* __restrict__ pb2,
    const float* __restrict__ gb0, const float* __restrict__ gb1,
    const float* __restrict__ gb2,
    unsigned short* __restrict__ Zb, unsigned short* __restrict__ Zpb,
    float* __restrict__ sqp2, const int* __restrict__ aidx,
    const float* __restrict__ gW0f) {
  __shared__ __align__(1024) char Hs[32768];   // 32 rows x 512 cols frag-major: slot (rf*16+ks)*1024
  const int tid = threadIdx.x, lane = tid & 63, wn = tid >> 6;
  const int l15 = lane & 15, hi = lane >> 4;
  const int z = blockIdx.y;
  const int bm = blockIdx.x * 32;
  const int lane16 = lane * 16;
  const char* Ab  = (const char*)(z ? SPb : Sb);
  const char* W0b = (const char*)(z ? gW0t : pW0t);
  const char* W1b = (const char*)(z ? gW1t : pW1t);
  const char* W2b = (const char*)(z ? gW2t : pW2t);
  const float* b0 = z ? gb0 : pb0;
  const float* b1 = z ? gb1 : pb1;
  const float* b2 = z ? gb2 : pb2;
  char* Cb = (char*)(z ? Zpb : Zb);

  int ar[2];
  ar[0] = aidx[bm + l15];
  ar[1] = aidx[bm + 16 + l15];

  // ---------- L0: K=256 (KS=8), out cols wn*128..+128 ----------
  {
    f32x4 acc[2][8] = {};
    bf16x8 bcur[8], acur[2];
#pragma unroll
    for (int jf = 0; jf < 8; ++jf)
      bcur[jf] = *(const bf16x8*)(W0b + (size_t)((wn * 8 + jf) * 8) * 1024 + lane16);
#pragma unroll
    for (int rf = 0; rf < 2; ++rf)
      acur[rf] = *(const bf16x8*)(Ab + (size_t)(((bm >> 4) + rf) * 8) * 1024 + lane16);
#pragma unroll
    for (int ks = 0; ks < 8; ++ks) {
      bf16x8 bnx[8], anx[2];
      if (ks < 7) {
#pragma unroll
        for (int jf = 0; jf < 8; ++jf)
          bnx[jf] = *(const bf16x8*)(W0b + (size_t)((wn * 8 + jf) * 8 + ks + 1) * 1024 + lane16);
#pragma unroll
        for (int rf = 0; rf < 2; ++rf)
          anx[rf] = *(const bf16x8*)(Ab + (size_t)(((bm >> 4) + rf) * 8 + ks + 1) * 1024 + lane16);
      }
#pragma unroll
      for (int rf = 0; rf < 2; ++rf)
#pragma unroll
        for (int jf = 0; jf < 8; ++jf)
          acc[rf][jf] = __builtin_amdgcn_mfma_f32_16x16x32_bf16(bcur[jf], acur[rf], acc[rf][jf], 0, 0, 0);
      if (ks < 7) {
#pragma unroll
        for (int jf = 0; jf < 8; ++jf) bcur[jf] = bnx[jf];
        acur[0] = anx[0]; acur[1] = anx[1];
      }
    }
    // epilogue -> H1 LDS frags
#pragma unroll
    for (int rf = 0; rf < 2; ++rf)
#pragma unroll
      for (int q = 0; q < 4; ++q) {
        const int col0 = wn * 128 + q * 32;
        float4 bi0 = *(const float4*)&b0[col0 + hi * 4];
        float4 bi1 = *(const float4*)&b0[col0 + 16 + hi * 4];
        float v[8] = { acc[rf][2 * q][0] + bi0.x, acc[rf][2 * q][1] + bi0.y,
                       acc[rf][2 * q][2] + bi0.z, acc[rf][2 * q][3] + bi0.w,
                       acc[rf][2 * q + 1][0] + bi1.x, acc[rf][2 * q + 1][1] + bi1.y,
                       acc[rf][2 * q + 1][2] + bi1.z, acc[rf][2 * q + 1][3] + bi1.w };
        if (z == 1) {
          float4 g0 = *(const float4*)&gW0f[(size_t)(256 + ar[rf]) * 512 + col0 + hi * 4];
          float4 g1 = *(const float4*)&gW0f[(size_t)(256 + ar[rf]) * 512 + col0 + 16 + hi * 4];
          v[0] += g0.x; v[1] += g0.y; v[2] += g0.z; v[3] += g0.w;
          v[4] += g1.x; v[5] += g1.y; v[6] += g1.z; v[7] += g1.w;
        }
        bf16x8 r;
#pragma unroll
        for (int t = 0; t < 8; ++t) r[t] = (short)f2bf(fmaxf(v[t], 0.f));
        *(bf16x8*)(Hs + ((rf * 16 + wn * 4 + q) * 1024) + lane16) = r;
      }
  }
  __syncthreads();

  // ---------- L1: K=512 (KS=16), A from LDS, out cols wn*128..+128 ----------
  {
    f32x4 acc[2][8] = {};
    bf16x8 bcur[8];
#pragma unroll
    for (int jf = 0; jf < 8; ++jf)
      bcur[jf] = *(const bf16x8*)(W1b + (size_t)((wn * 8 + jf) * 16) * 1024 + lane16);
#pragma unroll
    for (int ks = 0; ks < 16; ++ks) {
      bf16x8 bnx[8];
      if (ks < 15) {
#pragma unroll
        for (int jf = 0; jf < 8; ++jf)
          bnx[jf] = *(const bf16x8*)(W1b + (size_t)((wn * 8 + jf) * 16 + ks + 1) * 1024 + lane16);
      }
      bf16x8 a0 = *(const bf16x8*)(Hs + ((0 * 16 + ks) * 1024) + lane16);
      bf16x8 a1 = *(const bf16x8*)(Hs + ((1 * 16 + ks) * 1024) + lane16);
#pragma unroll
      for (int jf = 0; jf < 8; ++jf) {
        acc[0][jf] = __builtin_amdgcn_mfma_f32_16x16x32_bf16(bcur[jf], a0, acc[0][jf], 0, 0, 0);
        acc[1][jf] = __builtin_amdgcn_mfma_f32_16x16x32_bf16(bcur[jf], a1, acc[1][jf], 0, 0, 0);
      }
      if (ks < 15) {
#pragma unroll
        for (int jf = 0; jf < 8; ++jf) bcur[jf] = bnx[jf];
      }
    }
    __syncthreads();   // all H1 reads complete before overwrite
#pragma unroll
    for (int rf = 0; rf < 2; ++rf)
#pragma unroll
      for (int q = 0; q < 4; ++q) {
        const int col0 = wn * 128 + q * 32;
        float4 bi0 = *(const float4*)&b1[col0 + hi * 4];
        float4 bi1 = *(const float4*)&b1[col0 + 16 + hi * 4];
        float v[8] = { acc[rf][2 * q][0] + bi0.x, acc[rf][2 * q][1] + bi0.y,
                       acc[rf][2 * q][2] + bi0.z, acc[rf][2 * q][3] + bi0.w,
                       acc[rf][2 * q + 1][0] + bi1.x, acc[rf][2 * q + 1][1] + bi1.y,
                       acc[rf][2 * q + 1][2] + bi1.z, acc[rf][2 * q + 1][3] + bi1.w };
        bf16x8 r;
#pragma unroll
        for (int t = 0; t < 8; ++t) r[t] = (short)f2bf(fmaxf(v[t], 0.f));
        *(bf16x8*)(Hs + ((rf * 16 + wn * 4 + q) * 1024) + lane16) = r;
      }
  }
  __syncthreads();

  // ---------- L2: K=512 (KS=16), A from LDS, out cols wn*32..+32 ----------
  {
    f32x4 acc[2][2] = {};
    bf16x8 bcur[2];
#pragma unroll
    for (int fn = 0; fn < 2; ++fn)
      bcur[fn] = *(const bf16x8*)(W2b + (size_t)((wn * 2 + fn) * 16) * 1024 + lane16);
#pragma unroll
    for (int ks = 0; ks < 16; ++ks) {
      bf16x8 bnx[2];
      if (ks < 15) {
#pragma unroll
        for (int fn = 0; fn < 2; ++fn)
          bnx[fn] = *(const bf16x8*)(W2b + (size_t)((wn * 2 + fn) * 16 + ks + 1) * 1024 + lane16);
      }
      bf16x8 a0 = *(const bf16x8*)(Hs + ((0 * 16 + ks) * 1024) + lane16);
      bf16x8 a1 = *(const bf16x8*)(Hs + ((1 * 16 + ks) * 1024) + lane16);
#pragma unroll
      for (int fn = 0; fn < 2; ++fn) {
        acc[0][fn] = __builtin_amdgcn_mfma_f32_16x16x32_bf16(bcur[fn], a0, acc[0][fn], 0, 0, 0);
        acc[1][fn] = __builtin_amdgcn_mfma_f32_16x16x32_bf16(bcur[fn], a1, acc[1][fn], 0, 0, 0);
      }
      if (ks < 15) { bcur[0] = bnx[0]; bcur[1] = bnx[1]; }
    }
    const int col0 = wn * 32;
    float4 bi0 = *(const float4*)&b2[col0 + hi * 4];
    float4 bi1 = *(const float4*)&b2[col0 + 16 + hi * 4];
    float sq[2] = {0.f, 0.f};
#pragma unroll
    for (int rf = 0; rf < 2; ++rf) {
      float v[8] = { acc[rf][0][0] + bi0.x, acc[rf][0][1] + bi0.y,
                     acc[rf][0][2] + bi0.z, acc[rf][0][3] + bi0.w,
                     acc[rf][1][0] + bi1.x, acc[rf][1][1] + bi1.y,
                     acc[rf][1][2] + bi1.z, acc[rf][1][3] + bi1.w };
      bf16x8 r;
#pragma unroll
      for (int t = 0; t < 8; ++t) {
        unsigned short cv = f2bf(v[t]);
        r[t] = (short)cv;
        float vb = bf2f(cv);
        sq[rf] += vb * vb;
      }
      *(bf16x8*)(Cb + (size_t)((((bm >> 4) + rf) * 4 + wn) * 1024) + lane16) = r;
    }
    if (z == 1) {
#pragma unroll
      for (int rf = 0; rf < 2; ++rf) {
        float t = sq[rf];
        t += __shfl_xor(t, 16, 64);
        t += __shfl_xor(t, 32, 64);
        if (lane < 16) sqp2[(size_t)wn * NR + bm + rf * 16 + lane] = t;
      }
    }
  }
}

// ---------------------------------------------------------------- logits (R7 verbatim)
__global__ __launch_bounds__(256) void logits_fm(
    const unsigned short* __restrict__ Zb, const unsigned short* __restrict__ Zpb,
    const float* __restrict__ sqp2, float* __restrict__ wm_,
    float* __restrict__ wsum, float* __restrict__ wdiag) {
  const int tid = threadIdx.x, lane = tid & 63, w = tid >> 6;
  const int l15 = lane & 15, hi = lane >> 4;
  const int i0 = blockIdx.x * 128, jr = blockIdx.y;
  const int row32 = i0 + w * 32;
  const int jbase = jr * 128;
  const int lane16 = lane * 16;
  const char* Zc = (const char*)Zb;
  const char* Pc = (const char*)Zpb;

  bf16x8 afr[2][4];
#pragma unroll
  for (int rf = 0; rf < 2; ++rf)
#pragma unroll
    for (int ks = 0; ks < 4; ++ks)
      afr[rf][ks] = *(const bf16x8*)(Zc + (size_t)(((row32 >> 4) + rf) * 4 + ks) * 1024 + lane16);

  f32x4 acc[2][8] = {};
#pragma unroll
  for (int jf = 0; jf < 8; ++jf) {
    const size_t js = (size_t)((jbase >> 4) + jf) * 4;
#pragma unroll
    for (int ks = 0; ks < 4; ++ks) {
      bf16x8 bfv = *(const bf16x8*)(Pc + (js + ks) * 1024 + lane16);
      acc[0][jf] = __builtin_amdgcn_mfma_f32_16x16x32_bf16(bfv, afr[0][ks], acc[0][jf], 0, 0, 0);
      acc[1][jf] = __builtin_amdgcn_mfma_f32_16x16x32_bf16(bfv, afr[1][ks], acc[1][jf], 0, 0, 0);
    }
  }

#pragma unroll
  for (int rf = 0; rf < 2; ++rf) {
    const int grow = row32 + rf * 16 + l15;
    float mx = -INFINITY, dd = 0.f;
    bool hasd = false;
#pragma unroll
    for (int jf = 0; jf < 8; ++jf) {
      const int cb = jbase + jf * 16 + hi * 4;
      float4 q0 = *(const float4*)&sqp2[cb];
      float4 q1 = *(const float4*)&sqp2[NR + cb];
      float4 q2 = *(const float4*)&sqp2[2 * NR + cb];
      float4 q3 = *(const float4*)&sqp2[3 * NR + cb];
      float sp[4] = { q0.x + q1.x + q2.x + q3.x, q0.y + q1.y + q2.y + q3.y,
                      q0.z + q1.z + q2.z + q3.z, q0.w + q1.w + q2.w + q3.w };
#pragma unroll
      for (int e = 0; e < 4; ++e) {
        float lv = (2.f * acc[rf][jf][e] - sp[e]) * INV_T;
        acc[rf][jf][e] = lv;
        mx = fmaxf(mx, lv);
        if (cb + e == grow) { dd = lv; hasd = true; }
      }
    }
    mx = fmaxf(mx, __shfl_xor(mx, 16, 64));
    mx = fmaxf(mx, __shfl_xor(mx, 32, 64));
    float sum = 0.f;
#pragma unroll
    for (int jf = 0; jf < 8; ++jf)
#pragma unroll
      for (int e = 0; e < 4; ++e) sum += __expf(acc[rf][jf][e] - mx);
    sum += __shfl_xor(sum, 16, 64);
    sum += __shfl_xor(sum, 32, 64);
    if (hi == 0) {
      wm_[(size_t)jr * NR + grow] = mx;
      wsum[(size_t)jr * NR + grow] = sum;
    }
    if (hasd) wdiag[grow] = dd;
  }
}

// ---------------------------------------------------------------- finalize (R7 verbatim)
__global__ __launch_bounds__(256) void finalize(const float* __restrict__ wm,
    const float* __restrict__ wsum, const float* __restrict__ wdiag,
    float* __restrict__ out) {
  int r = blockIdx.x * 256 + threadIdx.x;
  float mm = wm[r];
  float ss = wsum[r];
#pragma unroll
  for (int p = 1; p < NJR; ++p) {
    float mo = wm[(size_t)p * NR + r];
    float so = wsum[(size_t)p * NR + r];
    float mn = fmaxf(mm, mo);
    ss = ss * __expf(mm - mn) + so * __expf(mo - mn);
    mm = mn;
  }
  float loss_r = mm + logf(ss) - wdiag[r];
  float v = loss_r;
#pragma unroll
  for (int off = 32; off; off >>= 1) v += __shfl_xor(v, off, 64);
  __shared__ float partial[4];
  if ((threadIdx.x & 63) == 0) partial[threadIdx.x >> 6] = v;
  __syncthreads();
  if (threadIdx.x == 0)
    atomicAdd(out, (partial[0] + partial[1] + partial[2] + partial[3]) * (1.0f / (float)NR));
}

// ---------------------------------------------------------------- launch
extern "C" void kernel_launch(void* const* d_in, const int* in_sizes, int n_in,
                              void* d_out, int out_size, void* d_ws, size_t ws_size,
                              hipStream_t stream) {
  const float* s   = (const float*)d_in[0];
  const float* sp  = (const float*)d_in[1];
  const float* a1h = (const float*)d_in[2];
  const float* pW0 = (const float*)d_in[3];
  const float* pb0 = (const float*)d_in[4];
  const float* pW1 = (const float*)d_in[5];
  const float* pb1 = (const float*)d_in[6];
  const float* pW2 = (const float*)d_in[7];
  const float* pb2 = (const float*)d_in[8];
  const float* gW0 = (const float*)d_in[9];
  const float* gb0 = (const float*)d_in[10];
  const float* gW1 = (const float*)d_in[11];
  const float* gb1 = (const float*)d_in[12];
  const float* gW2 = (const float*)d_in[13];
  const float* gb2 = (const float*)d_in[14];

  char* p = (char*)d_ws;
  unsigned short* Sb   = (unsigned short*)p; p += (size_t)NR * 256 * 2;
  unsigned short* SPb  = (unsigned short*)p; p += (size_t)NR * 256 * 2;
  unsigned short* Zall = (unsigned short*)p; p += (size_t)2 * NR * 128 * 2;
  unsigned short* pW0t = (unsigned short*)p; p += (size_t)256 * 512 * 2;
  unsigned short* pW1t = (unsigned short*)p; p += (size_t)512 * 512 * 2;
  unsigned short* pW2t = (unsigned short*)p; p += (size_t)512 * 128 * 2;
  unsigned short* gW0t = (unsigned short*)p; p += (size_t)256 * 512 * 2;
  unsigned short* gW1t = (unsigned short*)p; p += (size_t)512 * 512 * 2;
  unsigned short* gW2t = (unsigned short*)p; p += (size_t)512 * 128 * 2;
  float* sqp2 = (float*)p; p += (size_t)4 * NR * 4;
  float* wm   = (float*)p; p += (size_t)NJR * NR * 4;
  float* wsm  = (float*)p; p += (size_t)NJR * NR * 4;
  float* wdg  = (float*)p; p += (size_t)NR * 4;
  int*   aidx = (int*)p;  p += (size_t)NR * 4;

  unsigned short* Zb  = Zall;
  unsigned short* Zpb = Zall + (size_t)NR * 128;

  dim3 blk(256);
  prep<<<2960, blk, 0, stream>>>(s, sp, a1h, Sb, SPb, aidx,
                                 pW0, pW0t, pW1, pW1t, pW2, pW2t,
                                 gW0, gW0t, gW1, gW1t, gW2, gW2t,
                                 (float*)d_out);

  mlp_fused<<<dim3(NR / 32, 2), blk, 0, stream>>>(
      Sb, SPb, pW0t, pW1t, pW2t, gW0t, gW1t, gW2t,
      pb0, pb1, pb2, gb0, gb1, gb2,
      Zb, Zpb, sqp2, aidx, gW0);

  logits_fm<<<dim3(NR / 128, NJR), blk, 0, stream>>>(Zb, Zpb, sqp2, wm, wsm, wdg);
  finalize<<<NR / 256, blk, 0, stream>>>(wm, wsm, wdg, (float*)d_out);
}

// Round 10
// 57.319 us; speedup vs baseline: 5.2348x; 1.2420x over previous
//
#include <hip/hip_runtime.h>
#include <math.h>

#define NR 4096
#define HD 512
#define NJR 32
#define INV_T 10.0f

typedef __attribute__((ext_vector_type(8))) short bf16x8;
typedef __attribute__((ext_vector_type(4))) short short4v;
typedef __attribute__((ext_vector_type(4))) float f32x4;

typedef const unsigned int __attribute__((address_space(1)))* gas_t;
typedef unsigned int __attribute__((address_space(3)))* las_t;

__device__ __forceinline__ unsigned short f2bf(float f) {
  union { float f; unsigned u; } v; v.f = f;
  unsigned r = v.u + 0x7fff + ((v.u >> 16) & 1);
  return (unsigned short)(r >> 16);
}
__device__ __forceinline__ float bf2f(unsigned short b) {
  union { unsigned u; float f; } v; v.u = ((unsigned)b) << 16;
  return v.f;
}

// ======== fragment-major layout ========
// matrix [M][K]: fragment (rf=r>>4, ks=c>>5) = 1024B slot at (rf*(K>>5)+ks)*1024.
// lane l holds bf16x8 at lane*16: row = rf*16+(l&15), cols ks*32+(l>>4)*4+{0..3,16..19}.

// ---------------------------------------------------------------- prep (R7 + sqp zero)
__global__ __launch_bounds__(256) void prep(
    const float* __restrict__ s, const float* __restrict__ sp,
    const float* __restrict__ a1h,
    unsigned short* __restrict__ Sb, unsigned short* __restrict__ SPb,
    int* __restrict__ aidx, float* __restrict__ sqp,
    const float* __restrict__ pW0, unsigned short* __restrict__ pW0t,
    const float* __restrict__ pW1, unsigned short* __restrict__ pW1t,
    const float* __restrict__ pW2, unsigned short* __restrict__ pW2t,
    const float* __restrict__ gW0, unsigned short* __restrict__ gW0t,
    const float* __restrict__ gW1, unsigned short* __restrict__ gW1t,
    const float* __restrict__ gW2, unsigned short* __restrict__ gW2t,
    float* __restrict__ out) {
  int b = blockIdx.x, tid = threadIdx.x;
  if (b < 16) {
    int r = b * 256 + tid;
    int a = 0;
#pragma unroll
    for (int j = 0; j < 4; ++j) if (a1h[(size_t)r * 4 + j] > 0.5f) a = j;
    aidx[r] = a;
    sqp[r] = 0.f;
    if (b == 0 && tid == 0) out[0] = 0.f;
    return;
  }
  const int idx8 = tid & 127;
  const int h = idx8 & 1, p = idx8 >> 1, hi = p >> 4, l15 = p & 15;
  if (b < 2064) {
    const float* src = (b < 1040) ? s : sp;
    unsigned short* dst = (b < 1040) ? Sb : SPb;
    int lb = (b < 1040) ? b - 16 : b - 1040;
    int s0 = lb * 2 + (tid >> 7);
    int rf = s0 >> 3, ks = s0 & 7;
    int row = rf * 16 + l15, c0 = ks * 32 + hi * 4 + h * 16;
    float4 v = *(const float4*)&src[(size_t)row * 256 + c0];
    short4v o = { (short)f2bf(v.x), (short)f2bf(v.y), (short)f2bf(v.z), (short)f2bf(v.w) };
    *(short4v*)((char*)dst + (size_t)s0 * 1024 + idx8 * 8) = o;
    return;
  }
  int local = b - 2064;
  const float* W; unsigned short* Wt; int N, ksh;
  if (local < 128)      { W = pW0; Wt = pW0t; N = 512; ksh = 3; }
  else if (local < 384) { W = pW1; Wt = pW1t; N = 512; ksh = 4; local -= 128; }
  else if (local < 448) { W = pW2; Wt = pW2t; N = 128; ksh = 4; local -= 384; }
  else if (local < 576) { W = gW0; Wt = gW0t; N = 512; ksh = 3; local -= 448; }
  else if (local < 832) { W = gW1; Wt = gW1t; N = 512; ksh = 4; local -= 576; }
  else                  { W = gW2; Wt = gW2t; N = 128; ksh = 4; local -= 832; }
  int s0 = local * 2 + (tid >> 7);
  int rf = s0 >> ksh, ks = s0 & ((1 << ksh) - 1);
  int n = rf * 16 + l15, k0 = ks * 32 + hi * 4 + h * 16;
  short4v o = { (short)f2bf(W[(size_t)(k0 + 0) * N + n]),
                (short)f2bf(W[(size_t)(k0 + 1) * N + n]),
                (short)f2bf(W[(size_t)(k0 + 2) * N + n]),
                (short)f2bf(W[(size_t)(k0 + 3) * N + n]) };
  *(short4v*)((char*)Wt + (size_t)s0 * 1024 + idx8 * 8) = o;
}

// ---------------------------------------------------------------- small-tile dbuf GEMM
// BM x BN tile, BK=64, 4 waves (2x2). 2-deep global_load_lds pipeline, counted vmcnt.
template <int BM, int BN, int K, bool RELU, bool GB, bool SQ>
__global__ __launch_bounds__(256) void gemm_db(
    const unsigned short* __restrict__ A0, const unsigned short* __restrict__ A1,
    const unsigned short* __restrict__ W0, const unsigned short* __restrict__ W1,
    const float* __restrict__ b0, const float* __restrict__ b1,
    unsigned short* __restrict__ C0, unsigned short* __restrict__ C1,
    float* __restrict__ sqp, int N,
    const int* __restrict__ aidx, const float* __restrict__ gW0f) {
  constexpr int KS = K >> 5;
  constexpr int NSTEP = K >> 6;
  constexpr int ABY = BM * 128;
  constexpr int BBY = BN * 128;
  constexpr int RFW = BM >> 5;        // A frags / wave (also staged A slots / wave)
  constexpr int FNW = BN >> 5;        // B frags / wave
  constexpr int V = RFW + FNW;        // loads per wave per step
  __shared__ char lds[2 * (ABY + BBY)];
  char* As = lds;
  char* Bs = lds + 2 * ABY;

  const int tid = threadIdx.x, lane = tid & 63, w = tid >> 6;
  const int wm = w >> 1, wn = w & 1;
  const int z = blockIdx.z;
  const char* Ab = (const char*)(z ? A1 : A0);
  const char* Wb = (const char*)(z ? W1 : W0);
  const float* bias = z ? b1 : b0;
  char* Cb = (char*)(z ? C1 : C0);
  const int bm = blockIdx.x * BM, bn = blockIdx.y * BN;
  const int lane16 = lane * 16;

  auto stage = [&](int buf, int st) {
#pragma unroll
    for (int u = 0; u < RFW; ++u) {
      const int sl = w * RFW + u;
      const char* src = Ab + ((size_t)((bm >> 4) + (sl >> 1)) * KS + st * 2 + (sl & 1)) * 1024 + lane16;
      __builtin_amdgcn_global_load_lds((gas_t)src, (las_t)(As + buf * ABY + sl * 1024), 16, 0, 0);
    }
#pragma unroll
    for (int u = 0; u < FNW; ++u) {
      const int sl = w * FNW + u;
      const char* src = Wb + ((size_t)((bn >> 4) + (sl >> 1)) * KS + st * 2 + (sl & 1)) * 1024 + lane16;
      __builtin_amdgcn_global_load_lds((gas_t)src, (las_t)(Bs + buf * BBY + sl * 1024), 16, 0, 0);
    }
  };

  f32x4 acc[RFW][FNW] = {};
  stage(0, 0);
#pragma unroll
  for (int st = 0; st < NSTEP; ++st) {
    const int buf = st & 1;
    if (st + 1 < NSTEP) {
      stage(buf ^ 1, st + 1);
      if constexpr (V == 4) asm volatile("s_waitcnt vmcnt(4)" ::: "memory");
      else                  asm volatile("s_waitcnt vmcnt(3)" ::: "memory");
    } else {
      asm volatile("s_waitcnt vmcnt(0)" ::: "memory");
    }
    __builtin_amdgcn_s_barrier();
#pragma unroll
    for (int kss = 0; kss < 2; ++kss) {
      bf16x8 af[RFW], bfv[FNW];
#pragma unroll
      for (int i = 0; i < RFW; ++i)
        af[i] = *(const bf16x8*)(As + buf * ABY + ((wm * RFW + i) * 2 + kss) * 1024 + lane16);
#pragma unroll
      for (int j = 0; j < FNW; ++j)
        bfv[j] = *(const bf16x8*)(Bs + buf * BBY + ((wn * FNW + j) * 2 + kss) * 1024 + lane16);
#pragma unroll
      for (int i = 0; i < RFW; ++i)
#pragma unroll
        for (int j = 0; j < FNW; ++j)
          acc[i][j] = __builtin_amdgcn_mfma_f32_16x16x32_bf16(bfv[j], af[i], acc[i][j], 0, 0, 0);
    }
    __builtin_amdgcn_s_barrier();
  }

  // epilogue: lane&15 = out-row, hi*4+e = out-col within 16-col frag
  const int l15 = lane & 15, hi = lane >> 4;
  const int NS = N >> 5;
  const int row0 = bm + wm * (RFW * 16);
  const int col0 = bn + wn * (FNW * 16);
  int ar[RFW];
#pragma unroll
  for (int i = 0; i < RFW; ++i) ar[i] = 0;
  if (GB && z == 1) {
#pragma unroll
    for (int i = 0; i < RFW; ++i) ar[i] = aidx[row0 + i * 16 + l15];
  }
  if constexpr (FNW == 2) {
    float4 bi0 = *(const float4*)&bias[col0 + hi * 4];
    float4 bi1 = *(const float4*)&bias[col0 + 16 + hi * 4];
#pragma unroll
    for (int i = 0; i < RFW; ++i) {
      const int rfC = (row0 >> 4) + i;
      float v[8] = { acc[i][0][0] + bi0.x, acc[i][0][1] + bi0.y,
                     acc[i][0][2] + bi0.z, acc[i][0][3] + bi0.w,
                     acc[i][1][0] + bi1.x, acc[i][1][1] + bi1.y,
                     acc[i][1][2] + bi1.z, acc[i][1][3] + bi1.w };
      if (GB && z == 1) {
        float4 g0 = *(const float4*)&gW0f[(size_t)(256 + ar[i]) * N + col0 + hi * 4];
        float4 g1 = *(const float4*)&gW0f[(size_t)(256 + ar[i]) * N + col0 + 16 + hi * 4];
        v[0] += g0.x; v[1] += g0.y; v[2] += g0.z; v[3] += g0.w;
        v[4] += g1.x; v[5] += g1.y; v[6] += g1.z; v[7] += g1.w;
      }
      bf16x8 r;
#pragma unroll
      for (int t = 0; t < 8; ++t) {
        float vv = RELU ? fmaxf(v[t], 0.f) : v[t];
        r[t] = (short)f2bf(vv);
      }
      *(bf16x8*)(Cb + (size_t)(rfC * NS + (col0 >> 5)) * 1024 + lane16) = r;
    }
  } else {
    // FNW == 1: wave owns 16 cols = half a C-frag slot (elements wn*4..wn*4+3 of each 16B)
    float4 bi0 = *(const float4*)&bias[col0 + hi * 4];
    float sq[RFW];
#pragma unroll
    for (int i = 0; i < RFW; ++i) sq[i] = 0.f;
#pragma unroll
    for (int i = 0; i < RFW; ++i) {
      const int rfC = (row0 >> 4) + i;
      float v[4] = { acc[i][0][0] + bi0.x, acc[i][0][1] + bi0.y,
                     acc[i][0][2] + bi0.z, acc[i][0][3] + bi0.w };
      short4v r;
#pragma unroll
      for (int t = 0; t < 4; ++t) {
        float vv = RELU ? fmaxf(v[t], 0.f) : v[t];
        unsigned short cv = f2bf(vv);
        r[t] = (short)cv;
        if (SQ) { float vb = bf2f(cv); sq[i] += vb * vb; }
      }
      *(short4v*)(Cb + (size_t)(rfC * NS + (bn >> 5)) * 1024 + lane16 + wn * 8) = r;
    }
    if (SQ && z == 1) {
#pragma unroll
      for (int i = 0; i < RFW; ++i) {
        float t = sq[i];
        t += __shfl_xor(t, 16, 64);
        t += __shfl_xor(t, 32, 64);
        if (lane < 16) atomicAdd(&sqp[row0 + i * 16 + lane], t);
      }
    }
  }
}

// ---------------------------------------------------------------- logits (R7, sqp single array)
__global__ __launch_bounds__(256) void logits_fm(
    const unsigned short* __restrict__ Zb, const unsigned short* __restrict__ Zpb,
    const float* __restrict__ sqp, float* __restrict__ wm_,
    float* __restrict__ wsum, float* __restrict__ wdiag) {
  const int tid = threadIdx.x, lane = tid & 63, w = tid >> 6;
  const int l15 = lane & 15, hi = lane >> 4;
  const int i0 = blockIdx.x * 128, jr = blockIdx.y;
  const int row32 = i0 + w * 32;
  const int jbase = jr * 128;
  const int lane16 = lane * 16;
  const char* Zc = (const char*)Zb;
  const char* Pc = (const char*)Zpb;

  bf16x8 afr[2][4];
#pragma unroll
  for (int rf = 0; rf < 2; ++rf)
#pragma unroll
    for (int ks = 0; ks < 4; ++ks)
      afr[rf][ks] = *(const bf16x8*)(Zc + (size_t)(((row32 >> 4) + rf) * 4 + ks) * 1024 + lane16);

  f32x4 acc[2][8] = {};
#pragma unroll
  for (int jf = 0; jf < 8; ++jf) {
    const size_t js = (size_t)((jbase >> 4) + jf) * 4;
#pragma unroll
    for (int ks = 0; ks < 4; ++ks) {
      bf16x8 bfv = *(const bf16x8*)(Pc + (js + ks) * 1024 + lane16);
      acc[0][jf] = __builtin_amdgcn_mfma_f32_16x16x32_bf16(bfv, afr[0][ks], acc[0][jf], 0, 0, 0);
      acc[1][jf] = __builtin_amdgcn_mfma_f32_16x16x32_bf16(bfv, afr[1][ks], acc[1][jf], 0, 0, 0);
    }
  }

#pragma unroll
  for (int rf = 0; rf < 2; ++rf) {
    const int grow = row32 + rf * 16 + l15;
    float mx = -INFINITY, dd = 0.f;
    bool hasd = false;
#pragma unroll
    for (int jf = 0; jf < 8; ++jf) {
      const int cb = jbase + jf * 16 + hi * 4;
      float4 q = *(const float4*)&sqp[cb];
      float sp[4] = { q.x, q.y, q.z, q.w };
#pragma unroll
      for (int e = 0; e < 4; ++e) {
        float lv = (2.f * acc[rf][jf][e] - sp[e]) * INV_T;
        acc[rf][jf][e] = lv;
        mx = fmaxf(mx, lv);
        if (cb + e == grow) { dd = lv; hasd = true; }
      }
    }
    mx = fmaxf(mx, __shfl_xor(mx, 16, 64));
    mx = fmaxf(mx, __shfl_xor(mx, 32, 64));
    float sum = 0.f;
#pragma unroll
    for (int jf = 0; jf < 8; ++jf)
#pragma unroll
      for (int e = 0; e < 4; ++e) sum += __expf(acc[rf][jf][e] - mx);
    sum += __shfl_xor(sum, 16, 64);
    sum += __shfl_xor(sum, 32, 64);
    if (hi == 0) {
      wm_[(size_t)jr * NR + grow] = mx;
      wsum[(size_t)jr * NR + grow] = sum;
    }
    if (hasd) wdiag[grow] = dd;
  }
}

// ---------------------------------------------------------------- finalize (R7 verbatim)
__global__ __launch_bounds__(256) void finalize(const float* __restrict__ wm,
    const float* __restrict__ wsum, const float* __restrict__ wdiag,
    float* __restrict__ out) {
  int r = blockIdx.x * 256 + threadIdx.x;
  float mm = wm[r];
  float ss = wsum[r];
#pragma unroll
  for (int p = 1; p < NJR; ++p) {
    float mo = wm[(size_t)p * NR + r];
    float so = wsum[(size_t)p * NR + r];
    float mn = fmaxf(mm, mo);
    ss = ss * __expf(mm - mn) + so * __expf(mo - mn);
    mm = mn;
  }
  float loss_r = mm + logf(ss) - wdiag[r];
  float v = loss_r;
#pragma unroll
  for (int off = 32; off; off >>= 1) v += __shfl_xor(v, off, 64);
  __shared__ float partial[4];
  if ((threadIdx.x & 63) == 0) partial[threadIdx.x >> 6] = v;
  __syncthreads();
  if (threadIdx.x == 0)
    atomicAdd(out, (partial[0] + partial[1] + partial[2] + partial[3]) * (1.0f / (float)NR));
}

// ---------------------------------------------------------------- launch
extern "C" void kernel_launch(void* const* d_in, const int* in_sizes, int n_in,
                              void* d_out, int out_size, void* d_ws, size_t ws_size,
                              hipStream_t stream) {
  const float* s   = (const float*)d_in[0];
  const float* sp  = (const float*)d_in[1];
  const float* a1h = (const float*)d_in[2];
  const float* pW0 = (const float*)d_in[3];
  const float* pb0 = (const float*)d_in[4];
  const float* pW1 = (const float*)d_in[5];
  const float* pb1 = (const float*)d_in[6];
  const float* pW2 = (const float*)d_in[7];
  const float* pb2 = (const float*)d_in[8];
  const float* gW0 = (const float*)d_in[9];
  const float* gb0 = (const float*)d_in[10];
  const float* gW1 = (const float*)d_in[11];
  const float* gb1 = (const float*)d_in[12];
  const float* gW2 = (const float*)d_in[13];
  const float* gb2 = (const float*)d_in[14];

  char* p = (char*)d_ws;
  unsigned short* Sb   = (unsigned short*)p; p += (size_t)NR * 256 * 2;
  unsigned short* SPb  = (unsigned short*)p; p += (size_t)NR * 256 * 2;
  unsigned short* H1   = (unsigned short*)p; p += (size_t)2 * NR * HD * 2;
  unsigned short* H2   = (unsigned short*)p; p += (size_t)2 * NR * HD * 2;
  unsigned short* Zall = (unsigned short*)p; p += (size_t)2 * NR * 128 * 2;
  unsigned short* pW0t = (unsigned short*)p; p += (size_t)256 * 512 * 2;
  unsigned short* pW1t = (unsigned short*)p; p += (size_t)512 * 512 * 2;
  unsigned short* pW2t = (unsigned short*)p; p += (size_t)512 * 128 * 2;
  unsigned short* gW0t = (unsigned short*)p; p += (size_t)256 * 512 * 2;
  unsigned short* gW1t = (unsigned short*)p; p += (size_t)512 * 512 * 2;
  unsigned short* gW2t = (unsigned short*)p; p += (size_t)512 * 128 * 2;
  float* sqp  = (float*)p; p += (size_t)NR * 4;
  float* wm   = (float*)p; p += (size_t)NJR * NR * 4;
  float* wsm  = (float*)p; p += (size_t)NJR * NR * 4;
  float* wdg  = (float*)p; p += (size_t)NR * 4;
  int*   aidx = (int*)p;  p += (size_t)NR * 4;

  unsigned short* H1g = H1 + (size_t)NR * HD;
  unsigned short* H2g = H2 + (size_t)NR * HD;
  unsigned short* Zb  = Zall;
  unsigned short* Zpb = Zall + (size_t)NR * 128;

  dim3 blk(256);
  prep<<<2960, blk, 0, stream>>>(s, sp, a1h, Sb, SPb, aidx, sqp,
                                 pW0, pW0t, pW1, pW1t, pW2, pW2t,
                                 gW0, gW0t, gW1, gW1t, gW2, gW2t,
                                 (float*)d_out);

  gemm_db<64, 64, 256, true, true, false><<<dim3(64, 8, 2), blk, 0, stream>>>(
      Sb, SPb, pW0t, gW0t, pb0, gb0, H1, H1g, nullptr, 512, aidx, gW0);
  gemm_db<64, 64, 512, true, false, false><<<dim3(64, 8, 2), blk, 0, stream>>>(
      H1, H1g, pW1t, gW1t, pb1, gb1, H2, H2g, nullptr, 512, nullptr, nullptr);
  gemm_db<64, 32, 512, false, false, true><<<dim3(64, 4, 2), blk, 0, stream>>>(
      H2, H2g, pW2t, gW2t, pb2, gb2, Zb, Zpb, sqp, 128, nullptr, nullptr);

  logits_fm<<<dim3(NR / 128, NJR), blk, 0, stream>>>(Zb, Zpb, sqp, wm, wsm, wdg);
  finalize<<<NR / 256, blk, 0, stream>>>(wm, wsm, wdg, (float*)d_out);
}